// Round 3
// baseline (1283.186 us; speedup 1.0000x reference)
//
#include <hip/hip_runtime.h>

// ---------------------------------------------------------------------------
// HeterogeneousNormalizedAttentionBlock on MI355X (gfx950)
// B=4, LQ=LK=8192, E=256, H=8, D=32, NF=2, NE=4, HID=256;  M = B*LQ = 32768
// ---------------------------------------------------------------------------

typedef unsigned short u16;
typedef __attribute__((ext_vector_type(8))) short   bs8;    // 8 x bf16
typedef __attribute__((ext_vector_type(4))) float   f32x4;
typedef __attribute__((ext_vector_type(16))) float  f32x16;

__device__ __forceinline__ float bf2f(u16 u) {
  union { float f; unsigned i; } c; c.i = ((unsigned)u) << 16; return c.f;
}
__device__ __forceinline__ u16 f2bf(float f) {
  union { float f; unsigned i; } c; c.f = f;
  unsigned x = c.i;
  return (u16)((x + 0x7fffu + ((x >> 16) & 1u)) >> 16);   // RNE
}
__device__ __forceinline__ unsigned pack2(float a, float b) {
  return (unsigned)f2bf(a) | ((unsigned)f2bf(b) << 16);
}
__device__ __forceinline__ float gelu_f(float x) {
  // tanh-form GELU: 0.5x(1+tanh(0.79788(x+0.044715x^3))) = x*sigmoid(2t)
  const float t = x * (0.7978845608f + 0.0356774081f * x * x);
  return x / (1.f + __expf(-2.f * t));
}

#define EPI_PLAIN 0
#define EPI_GELU  1
#define EPI_CINIT 2
#define EPI_CACC  3
#define EPI_QSM   4   // feature-dim softmax over 32-col head groups

// ---------------------------------------------------------------------------
// Workhorse GEMM: C(M,256) = epi(A(M,256) @ W(256,256)^T + bias)
// BM=BN=128, BK=64, 4 waves (2x2), wave 64x64. XOR-swizzled LDS.
// Double-buffered LDS + 1-ahead register prefetch, 1 barrier per K-step.
// ---------------------------------------------------------------------------
template <bool AF32, int EPI>
__global__ __launch_bounds__(256, 2) void gemm256(
    const void* __restrict__ Ain, const u16* __restrict__ W,
    const float* __restrict__ bias, u16* __restrict__ outb,
    float* __restrict__ outf, const float* __restrict__ csrc,
    const float* __restrict__ scores, int expert) {
  __shared__ int4 ash[2][1024];  // 128 x 64 bf16 per buffer, swizzled
  __shared__ int4 wsh[2][1024];
  const int tid = threadIdx.x;
  const int m0 = blockIdx.x * 128, n0 = blockIdx.y * 128;
  const int wave = tid >> 6, lane = tid & 63;
  const int wm = (wave >> 1) * 64, wn = (wave & 1) * 64;
  const int lr = lane & 15, lk = lane >> 4;
  f32x4 acc[4][4];
#pragma unroll
  for (int m = 0; m < 4; ++m)
#pragma unroll
    for (int n = 0; n < 4; ++n) acc[m][n] = f32x4{0.f, 0.f, 0.f, 0.f};

  const float* Af = (const float*)Ain;
  const u16*   Ab = (const u16*)Ain;

  int4 areg[4], wreg[4];
  float4 aregf[8];

  auto LOAD = [&](int kt) {
#pragma unroll
    for (int it = 0; it < 4; ++it) {
      const int s = tid + it * 256;
      const int row = s >> 3, c16 = s & 7;
      const long srcA = (long)(m0 + row) * 256 + kt * 64 + c16 * 8;
      if constexpr (AF32) {
        const float4* p = (const float4*)(Af + srcA);
        aregf[2 * it]     = p[0];
        aregf[2 * it + 1] = p[1];
      } else {
        areg[it] = *(const int4*)(Ab + srcA);
      }
      wreg[it] = *(const int4*)(W + (long)(n0 + row) * 256 + kt * 64 + c16 * 8);
    }
  };
  auto WRITE = [&](int buf) {
#pragma unroll
    for (int it = 0; it < 4; ++it) {
      const int s = tid + it * 256;
      const int row = s >> 3, c16 = s & 7;
      const int dst = (row << 3) | (c16 ^ (row & 7));
      int4 val;
      if constexpr (AF32) {
        const float4 x = aregf[2 * it], y = aregf[2 * it + 1];
        val.x = pack2(x.x, x.y); val.y = pack2(x.z, x.w);
        val.z = pack2(y.x, y.y); val.w = pack2(y.z, y.w);
      } else {
        val = areg[it];
      }
      ash[buf][dst] = val;
      wsh[buf][dst] = wreg[it];
    }
  };

  LOAD(0); WRITE(0);
  __syncthreads();
  for (int kt = 0; kt < 4; ++kt) {
    if (kt < 3) LOAD(kt + 1);     // in flight during MFMA phase
    const int cur = kt & 1;
#pragma unroll
    for (int kk = 0; kk < 2; ++kk) {
      bs8 af[4], wf[4];
#pragma unroll
      for (int m = 0; m < 4; ++m) {
        const int row = wm + m * 16 + lr;
        af[m] = *(const bs8*)&ash[cur][(row << 3) | ((kk * 4 + lk) ^ (row & 7))];
      }
#pragma unroll
      for (int n = 0; n < 4; ++n) {
        const int row = wn + n * 16 + lr;
        wf[n] = *(const bs8*)&wsh[cur][(row << 3) | ((kk * 4 + lk) ^ (row & 7))];
      }
#pragma unroll
      for (int m = 0; m < 4; ++m)
#pragma unroll
        for (int n = 0; n < 4; ++n)
          acc[m][n] = __builtin_amdgcn_mfma_f32_16x16x32_bf16(af[m], wf[n],
                                                              acc[m][n], 0, 0, 0);
    }
    if (kt < 3) WRITE(cur ^ 1);
    __syncthreads();
  }
  // ---- epilogue ----
  if constexpr (EPI == EPI_QSM) {
#pragma unroll
    for (int m = 0; m < 4; ++m) {
      const int rb = m0 + wm + m * 16 + lk * 4;
#pragma unroll
      for (int j = 0; j < 4; ++j) {
#pragma unroll
        for (int hh = 0; hh < 2; ++hh) {
          const int c0 = n0 + wn + (2 * hh) * 16 + lr;
          const float p0 = __expf(acc[m][2 * hh][j] + bias[c0]);
          const float p1 = __expf(acc[m][2 * hh + 1][j] + bias[c0 + 16]);
          float s = p0 + p1;
#pragma unroll
          for (int o = 8; o >= 1; o >>= 1) s += __shfl_xor(s, o);
          const float inv = 1.0f / s;
          outb[(long)(rb + j) * 256 + c0]      = f2bf(p0 * inv);
          outb[(long)(rb + j) * 256 + c0 + 16] = f2bf(p1 * inv);
        }
      }
    }
  } else {
#pragma unroll
    for (int m = 0; m < 4; ++m) {
      const int rb = m0 + wm + m * 16 + lk * 4;
#pragma unroll
      for (int n = 0; n < 4; ++n) {
        const int gc = n0 + wn + n * 16 + lr;
        const float bv = bias[gc];
#pragma unroll
        for (int j = 0; j < 4; ++j) {
          const long idx = (long)(rb + j) * 256 + gc;
          float v = acc[m][n][j] + bv;
          if constexpr (EPI == EPI_GELU) v = gelu_f(v);
          if constexpr (EPI == EPI_PLAIN || EPI == EPI_GELU) {
            outb[idx] = f2bf(v);
          } else {
            const float sc = scores[(long)(rb + j) * 4 + expert];
            float base;
            if constexpr (EPI == EPI_CINIT) base = csrc[idx];
            else                            base = outf[idx];
            outf[idx] = base + sc * v;
          }
        }
      }
    }
  }
}

// ---------------------------------------------------------------------------
// kvstats: fused {K-proj, V-proj, K-softmax, per-head stats}.
// Emits tmpT[h][dv][dk] (swapped MFMA operands: V^T @ Kn) and ksum[h][dk].
// ---------------------------------------------------------------------------
__global__ __launch_bounds__(1024, 4) void kvstats(
    const float* __restrict__ Ain, const u16* __restrict__ Wk,
    const u16* __restrict__ Wv, const float* __restrict__ bk,
    const float* __restrict__ bv, float* __restrict__ pks,
    float* __restrict__ ptm) {
  __shared__ __align__(16) char smem[73728];
  int4* ash  = (int4*)smem;        // 512 slots  (64x64 bf16)
  int4* wksh = ash + 512;          // 2048 slots (256x64)
  int4* wvsh = wksh + 2048;        // 2048 slots
  u16* KnT = (u16*)smem;           // [256][72] bf16 (transposed, padded)
  u16* VT  = KnT + 256 * 72;
  const int tid = threadIdx.x;
  const int wave = tid >> 6, lane = tid & 63;
  const int lr = lane & 15, lk = lane >> 4;
  const int kvsel = wave >> 3, w3 = wave & 7;
  const int wm = (w3 >> 2) * 32, wn = (w3 & 3) * 64;
  const int b = blockIdx.y, ch = blockIdx.x;
  const long r0 = (long)b * 8192 + (long)ch * 64;

  f32x4 acc[2][4];
#pragma unroll
  for (int m = 0; m < 2; ++m)
#pragma unroll
    for (int n = 0; n < 4; ++n) acc[m][n] = f32x4{0.f, 0.f, 0.f, 0.f};

  for (int kt = 0; kt < 4; ++kt) {
    const int k0 = kt * 64;
    if (kt) __syncthreads();
    if (tid < 512) {  // A tile 64x64 fp32 -> bf16
      const int row = tid >> 3, c16 = tid & 7;
      const int dst = (row << 3) | (c16 ^ (row & 7));
      const float4* p = (const float4*)(Ain + (r0 + row) * 256 + k0 + c16 * 8);
      const float4 x = p[0], y = p[1];
      int4 val;
      val.x = pack2(x.x, x.y); val.y = pack2(x.z, x.w);
      val.z = pack2(y.x, y.y); val.w = pack2(y.z, y.w);
      ash[dst] = val;
    }
#pragma unroll
    for (int it = 0; it < 2; ++it) {  // Wk + Wv tiles 256x64
      const int s = tid + it * 1024;
      const int row = s >> 3, c16 = s & 7;
      const int dst = (row << 3) | (c16 ^ (row & 7));
      wksh[dst] = *(const int4*)(Wk + (long)row * 256 + k0 + c16 * 8);
      wvsh[dst] = *(const int4*)(Wv + (long)row * 256 + k0 + c16 * 8);
    }
    __syncthreads();
    const int4* wsh = kvsel ? wvsh : wksh;
#pragma unroll
    for (int kk = 0; kk < 2; ++kk) {
      bs8 af[2], wf[4];
#pragma unroll
      for (int m = 0; m < 2; ++m) {
        const int row = wm + m * 16 + lr;
        af[m] = *(const bs8*)&ash[(row << 3) | ((kk * 4 + lk) ^ (row & 7))];
      }
#pragma unroll
      for (int n = 0; n < 4; ++n) {
        const int row = wn + n * 16 + lr;
        wf[n] = *(const bs8*)&wsh[(row << 3) | ((kk * 4 + lk) ^ (row & 7))];
      }
#pragma unroll
      for (int m = 0; m < 2; ++m)
#pragma unroll
        for (int n = 0; n < 4; ++n)
          acc[m][n] = __builtin_amdgcn_mfma_f32_16x16x32_bf16(af[m], wf[n],
                                                              acc[m][n], 0, 0, 0);
    }
  }
  __syncthreads();  // GEMM LDS dead; reuse as KnT/VT

  const float* bias = kvsel ? bv : bk;
  if (kvsel == 0) {
#pragma unroll
    for (int m = 0; m < 2; ++m)
#pragma unroll
      for (int j = 0; j < 4; ++j)
#pragma unroll
        for (int hh = 0; hh < 2; ++hh) {
          const int c0 = wn + (2 * hh) * 16 + lr;
          const float p0 = __expf(acc[m][2 * hh][j] + bias[c0]);
          const float p1 = __expf(acc[m][2 * hh + 1][j] + bias[c0 + 16]);
          float s = p0 + p1;
#pragma unroll
          for (int o = 8; o >= 1; o >>= 1) s += __shfl_xor(s, o);
          const float inv = 1.0f / s;
          acc[m][2 * hh][j] = p0 * inv;
          acc[m][2 * hh + 1][j] = p1 * inv;
        }
  }
  {
    u16* T = kvsel ? VT : KnT;
#pragma unroll
    for (int m = 0; m < 2; ++m) {
      const int rb = wm + m * 16 + lk * 4;
#pragma unroll
      for (int n = 0; n < 4; ++n) {
        const int col = wn + n * 16 + lr;
        float v0 = acc[m][n][0], v1 = acc[m][n][1];
        float v2 = acc[m][n][2], v3 = acc[m][n][3];
        if (kvsel) {
          const float bb = bias[col];
          v0 += bb; v1 += bb; v2 += bb; v3 += bb;
        }
        uint2 w;
        w.x = pack2(v0, v1); w.y = pack2(v2, v3);
        *(uint2*)(T + col * 72 + rb) = w;
      }
    }
  }
  __syncthreads();

  if (kvsel == 0) {  // stats: wave w3 = head h
    const int h = w3;
    f32x16 aT, aK;
#pragma unroll
    for (int r = 0; r < 16; ++r) { aT[r] = 0.f; aK[r] = 0.f; }
    bs8 ones;
#pragma unroll
    for (int e = 0; e < 8; ++e) ones[e] = (short)0x3F80;
    const u16* kcol = KnT + (h * 32 + (lane & 31)) * 72;
    const u16* vcol = VT  + (h * 32 + (lane & 31)) * 72;
    const int hi8 = (lane >> 5) * 8;
#pragma unroll
    for (int ks = 0; ks < 4; ++ks) {
      const bs8 a  = *(const bs8*)(kcol + ks * 16 + hi8);
      const bs8 vb = *(const bs8*)(vcol + ks * 16 + hi8);
      aT = __builtin_amdgcn_mfma_f32_32x32x16_bf16(vb, a, aT, 0, 0, 0);  // tmpT
      aK = __builtin_amdgcn_mfma_f32_32x32x16_bf16(a, ones, aK, 0, 0, 0);
    }
    const long blk = (long)b * gridDim.x + ch;
    float* po = ptm + blk * 8192 + h * 1024;
#pragma unroll
    for (int r = 0; r < 16; ++r) {
      const int dv = (r & 3) + 8 * (r >> 2) + 4 * (lane >> 5);
      po[dv * 32 + (lane & 31)] = aT[r];   // tmpT[h][dv][dk]
    }
    if ((lane & 31) == 0) {
#pragma unroll
      for (int r = 0; r < 16; ++r) {
        const int dk = (r & 3) + 8 * (r >> 2) + 4 * (lane >> 5);
        pks[blk * 256 + h * 32 + dk] = aK[r];
      }
    }
  }
}

// deterministic reduce of the 128 chunk-partials for ONE f
__global__ void reduceStats(const float* __restrict__ pk,
                            const float* __restrict__ pt,
                            float* __restrict__ ksum, float* __restrict__ tmp) {
  const int b = blockIdx.y;
  const int i = blockIdx.x * 256 + threadIdx.x;  // 0..8447
  float s = 0.f;
  if (i < 256) {
    const float* p = pk + (long)b * 128 * 256 + i;
    for (int c = 0; c < 128; ++c) s += p[c * 256];
    ksum[(long)b * 256 + i] = s;
  } else {
    const int j = i - 256;
    const float* p = pt + (long)b * 128 * 8192 + j;
    for (int c = 0; c < 128; ++c) s += p[c * 8192];
    tmp[(long)b * 8192 + j] = s;
  }
}

// ---------------------------------------------------------------------------
// mixk (MFMA): per head h, B panel = [tmpT_f (32F) | I (32) | ksum cols (16)].
// D = q_h @ B gives {q@tmp_f, q (residual), alpha-dots} in one shot.
// out = q + (1/F) * sum_f (q@tmp_f)/alpha_f.  Block = 64 rows, 4 waves.
// ---------------------------------------------------------------------------
template <int F>
__global__ __launch_bounds__(256, 2) void mixk(const u16* __restrict__ q,
                                               const float* __restrict__ ksum,
                                               const float* __restrict__ tmp,
                                               u16* __restrict__ out) {
  constexpr int NCOL = F * 32 + 32 + 16;   // F=2:112, F=1:80
  constexpr int NFR  = NCOL / 16;
  __shared__ u16 bh[8 * NCOL * 32];
  const int tid = threadIdx.x, lane = tid & 63, w = tid >> 6;
  const int lr = lane & 15, lk = lane >> 4;
  const int b = blockIdx.y;
  for (int i = tid; i < 8 * NCOL * 32; i += 256) {
    const int h = i / (NCOL * 32);
    const int rem = i % (NCOL * 32);
    const int n = rem >> 5, k = rem & 31;
    float val;
    if (n < F * 32) {
      const int f = n >> 5, dv = n & 31;
      val = tmp[((long)f * 4 + b) * 8192 + h * 1024 + dv * 32 + k];
    } else if (n < F * 32 + 32) {
      val = (n - F * 32 == k) ? 1.0f : 0.0f;
    } else {
      const int c = n - F * 32 - 32;
      val = (c < F) ? ksum[((long)c * 4 + b) * 256 + h * 32 + k] : 0.0f;
    }
    bh[i] = f2bf(val);
  }
  __syncthreads();
  const long rowg = (long)b * 8192 + (long)blockIdx.x * 64 + w * 16;
  bs8 af[8];
#pragma unroll
  for (int h = 0; h < 8; ++h)
    af[h] = *(const bs8*)(q + (rowg + lr) * 256 + h * 32 + lk * 8);
#pragma unroll
  for (int h = 0; h < 8; ++h) {
    f32x4 d[NFR];
#pragma unroll
    for (int n = 0; n < NFR; ++n) d[n] = f32x4{0.f, 0.f, 0.f, 0.f};
#pragma unroll
    for (int n = 0; n < NFR; ++n) {
      const bs8 bf = *(const bs8*)&bh[(h * NCOL + n * 16 + lr) * 32 + lk * 8];
      d[n] = __builtin_amdgcn_mfma_f32_16x16x32_bf16(af[h], bf, d[n], 0, 0, 0);
    }
#pragma unroll
    for (int j = 0; j < 4; ++j) {
      const long orow = rowg + lk * 4 + j;
      if constexpr (F == 2) {
        const float a0 = __shfl(d[6][j], (lane & 48));
        const float a1 = __shfl(d[6][j], (lane & 48) | 1);
#pragma unroll
        for (int nn = 0; nn < 2; ++nn) {
          const float v = d[4 + nn][j] + 0.5f * (d[nn][j] / a0 + d[2 + nn][j] / a1);
          out[orow * 256 + h * 32 + nn * 16 + lr] = f2bf(v);
        }
      } else {
        const float a0 = __shfl(d[4][j], (lane & 48));
#pragma unroll
        for (int nn = 0; nn < 2; ++nn) {
          const float v = d[2 + nn][j] + d[nn][j] / a0;
          out[orow * 256 + h * 32 + nn * 16 + lr] = f2bf(v);
        }
      }
    }
  }
}

// pre-convert the 34 (256x256) weight matrices to bf16
struct WTab { const float* p[34]; };
__global__ void convW(WTab tab, u16* __restrict__ dst) {
  const int s = blockIdx.y;
  const long i = ((long)blockIdx.x * 256 + threadIdx.x) * 4;
  const float4 v = *(const float4*)(tab.p[s] + i);
  ushort4 o;
  o.x = f2bf(v.x); o.y = f2bf(v.y); o.z = f2bf(v.z); o.w = f2bf(v.w);
  *(ushort4*)(dst + (long)s * 65536 + i) = o;
}

// ---------------------------------------------------------------------------
extern "C" void kernel_launch(void* const* d_in, const int* in_sizes, int n_in,
                              void* d_out, int out_size, void* d_ws, size_t ws_size,
                              hipStream_t stream) {
  (void)in_sizes; (void)n_in; (void)out_size; (void)ws_size;
  const float* scores = (const float*)d_in[0];
  const float* query  = (const float*)d_in[1];
  const float* IF     = (const float*)d_in[2];
  const float* ca_Wq = (const float*)d_in[3];  const float* ca_bq = (const float*)d_in[4];
  const float* ca_Wk = (const float*)d_in[5];  const float* ca_bk = (const float*)d_in[6];
  const float* ca_Wv = (const float*)d_in[7];  const float* ca_bv = (const float*)d_in[8];
  const float* ca_Wo = (const float*)d_in[9];  const float* ca_bo = (const float*)d_in[10];
  const float* sa_Wq = (const float*)d_in[11]; const float* sa_bq = (const float*)d_in[12];
  const float* sa_Wk = (const float*)d_in[13]; const float* sa_bk = (const float*)d_in[14];
  const float* sa_Wv = (const float*)d_in[15]; const float* sa_bv = (const float*)d_in[16];
  const float* sa_Wo = (const float*)d_in[17]; const float* sa_bo = (const float*)d_in[18];
  const float* f1W1 = (const float*)d_in[19]; const float* f1b1 = (const float*)d_in[20];
  const float* f1W2 = (const float*)d_in[21]; const float* f1b2 = (const float*)d_in[22];
  const float* f1W3 = (const float*)d_in[23]; const float* f1b3 = (const float*)d_in[24];
  const float* f2W1 = (const float*)d_in[25]; const float* f2b1 = (const float*)d_in[26];
  const float* f2W2 = (const float*)d_in[27]; const float* f2b2 = (const float*)d_in[28];
  const float* f2W3 = (const float*)d_in[29]; const float* f2b3 = (const float*)d_in[30];

  char* ws = (char*)d_ws;
  u16* X0 = (u16*)(ws);                   // (M,256) bf16, 16 MiB each
  u16* X1 = (u16*)(ws + 16777216);
  u16* X2 = (u16*)(ws + 33554432);
  u16* X3 = (u16*)(ws + 50331648);        // FFN intermediate; doubles as ptm
  float* ptmX3 = (float*)(ws + 50331648); // 4b x 128ch x 8192 f32 = 16.78 MB
  u16* W16 = (u16*)(ws + 67108864);       // 34 * 65536 bf16
  float* ksum = (float*)(ws + 71565312);  // [F*B][256]
  float* tmpb = (float*)(ws + 71573504);  // [F*B][8192]  (tmpT layout)
  float* pks  = (float*)(ws + 71835648);  // partial ksum
  float* qacc = (float*)d_out;            // fp32 accumulator = output

  WTab tab;
  tab.p[0] = ca_Wq; tab.p[1] = ca_Wk; tab.p[2] = ca_Wk + 65536;
  tab.p[3] = ca_Wv; tab.p[4] = ca_Wv + 65536; tab.p[5] = ca_Wo;
  tab.p[6] = sa_Wq; tab.p[7] = sa_Wk; tab.p[8] = sa_Wv; tab.p[9] = sa_Wo;
  for (int e = 0; e < 4; ++e) {
    tab.p[10 + e] = f1W1 + e * 65536; tab.p[14 + e] = f1W2 + e * 65536;
    tab.p[18 + e] = f1W3 + e * 65536; tab.p[22 + e] = f2W1 + e * 65536;
    tab.p[26 + e] = f2W2 + e * 65536; tab.p[30 + e] = f2W3 + e * 65536;
  }
  convW<<<dim3(64, 34), 256, 0, stream>>>(tab, W16);

  const dim3 gg(256, 2), gb(256);
  const dim3 kvg(128, 4), kvb(1024);
  // ---- cross attention ----
  gemm256<true, EPI_QSM><<<gg, gb, 0, stream>>>(query, W16 + 0 * 65536L, ca_bq, X0, nullptr, nullptr, nullptr, 0);
  for (int f = 0; f < 2; ++f) {
    kvstats<<<kvg, kvb, 0, stream>>>(IF + (long)f * 8388608,
                                     W16 + (1 + f) * 65536L, W16 + (3 + f) * 65536L,
                                     ca_bk + f * 256, ca_bv + f * 256, pks, ptmX3);
    reduceStats<<<dim3(33, 4), 256, 0, stream>>>(pks, ptmX3, ksum + f * 4 * 256, tmpb + (long)f * 4 * 8192);
  }
  mixk<2><<<dim3(128, 4), 256, 0, stream>>>(X0, ksum, tmpb, X1);
  gemm256<false, EPI_PLAIN><<<gg, gb, 0, stream>>>(X1, W16 + 5 * 65536L, ca_bo, X2, nullptr, nullptr, nullptr, 0);
  for (int e = 0; e < 4; ++e) {  // FFN1 + combine into qacc, init from query
    gemm256<false, EPI_GELU><<<gg, gb, 0, stream>>>(X2, W16 + (10 + e) * 65536L, f1b1 + e * 256, X0, nullptr, nullptr, nullptr, 0);
    gemm256<false, EPI_GELU><<<gg, gb, 0, stream>>>(X0, W16 + (14 + e) * 65536L, f1b2 + e * 256, X3, nullptr, nullptr, nullptr, 0);
    if (e == 0)
      gemm256<false, EPI_CINIT><<<gg, gb, 0, stream>>>(X3, W16 + (18 + e) * 65536L, f1b3 + e * 256, nullptr, qacc, query, scores, e);
    else
      gemm256<false, EPI_CACC><<<gg, gb, 0, stream>>>(X3, W16 + (18 + e) * 65536L, f1b3 + e * 256, nullptr, qacc, nullptr, scores, e);
  }
  // ---- self attention ----
  gemm256<true, EPI_QSM><<<gg, gb, 0, stream>>>(qacc, W16 + 6 * 65536L, sa_bq, X0, nullptr, nullptr, nullptr, 0);
  kvstats<<<kvg, kvb, 0, stream>>>(qacc, W16 + 7 * 65536L, W16 + 8 * 65536L,
                                   sa_bk, sa_bv, pks, ptmX3);
  reduceStats<<<dim3(33, 4), 256, 0, stream>>>(pks, ptmX3, ksum, tmpb);
  mixk<1><<<dim3(128, 4), 256, 0, stream>>>(X0, ksum, tmpb, X1);
  gemm256<false, EPI_PLAIN><<<gg, gb, 0, stream>>>(X1, W16 + 9 * 65536L, sa_bo, X2, nullptr, nullptr, nullptr, 0);
  for (int e = 0; e < 4; ++e) {  // FFN2 + combine (in place on qacc)
    gemm256<false, EPI_GELU><<<gg, gb, 0, stream>>>(X2, W16 + (22 + e) * 65536L, f2b1 + e * 256, X0, nullptr, nullptr, nullptr, 0);
    gemm256<false, EPI_GELU><<<gg, gb, 0, stream>>>(X0, W16 + (26 + e) * 65536L, f2b2 + e * 256, X3, nullptr, nullptr, nullptr, 0);
    if (e == 0)
      gemm256<false, EPI_CINIT><<<gg, gb, 0, stream>>>(X3, W16 + (30 + e) * 65536L, f2b3 + e * 256, nullptr, qacc, qacc, scores, e);
    else
      gemm256<false, EPI_CACC><<<gg, gb, 0, stream>>>(X3, W16 + (30 + e) * 65536L, f2b3 + e * 256, nullptr, qacc, nullptr, scores, e);
  }
}

// Round 4
// 564.079 us; speedup vs baseline: 2.2748x; 2.2748x over previous
//
#include <hip/hip_runtime.h>

// ---------------------------------------------------------------------------
// HeterogeneousNormalizedAttentionBlock on MI355X (gfx950)
// B=4, LQ=LK=8192, E=256, H=8, D=32, NF=2, NE=4, HID=256;  M = B*LQ = 32768
// ---------------------------------------------------------------------------

typedef unsigned short u16;
typedef __attribute__((ext_vector_type(8))) short   bs8;    // 8 x bf16
typedef __attribute__((ext_vector_type(4))) float   f32x4;
typedef __attribute__((ext_vector_type(16))) float  f32x16;

__device__ __forceinline__ float bf2f(u16 u) {
  union { float f; unsigned i; } c; c.i = ((unsigned)u) << 16; return c.f;
}
__device__ __forceinline__ u16 f2bf(float f) {
  union { float f; unsigned i; } c; c.f = f;
  unsigned x = c.i;
  return (u16)((x + 0x7fffu + ((x >> 16) & 1u)) >> 16);   // RNE
}
__device__ __forceinline__ unsigned pack2(float a, float b) {
  return (unsigned)f2bf(a) | ((unsigned)f2bf(b) << 16);
}
__device__ __forceinline__ float gelu_f(float x) {
  const float t = x * (0.7978845608f + 0.0356774081f * x * x);
  return x / (1.f + __expf(-2.f * t));
}

#define EPI_PLAIN 0
#define EPI_GELU  1
#define EPI_CINIT 2
#define EPI_CACC  3
#define EPI_QSM   4   // feature-dim softmax over 32-col head groups

// ---------------------------------------------------------------------------
// Workhorse GEMM: C(M,256) = epi(A(M,256) @ W(256,256)^T + bias)
// BM=BN=128, BK=64, 4 waves (2x2), wave 64x64. XOR-swizzled LDS.
// (round-2 structure: simple 2-barrier K-loop — dbuf attempt regressed, m99)
// ---------------------------------------------------------------------------
template <bool AF32, int EPI>
__global__ __launch_bounds__(256, 2) void gemm256(
    const void* __restrict__ Ain, const u16* __restrict__ W,
    const float* __restrict__ bias, u16* __restrict__ outb,
    float* __restrict__ outf, const float* __restrict__ csrc,
    const float* __restrict__ scores, int expert) {
  __shared__ int4 ash[1024];  // 128 x 64 bf16, swizzled
  __shared__ int4 wsh[1024];
  const int tid = threadIdx.x;
  const int m0 = blockIdx.x * 128, n0 = blockIdx.y * 128;
  const int wave = tid >> 6, lane = tid & 63;
  const int wm = (wave >> 1) * 64, wn = (wave & 1) * 64;
  const int lr = lane & 15, lk = lane >> 4;
  f32x4 acc[4][4];
#pragma unroll
  for (int m = 0; m < 4; ++m)
#pragma unroll
    for (int n = 0; n < 4; ++n) acc[m][n] = f32x4{0.f, 0.f, 0.f, 0.f};

  const float* Af = (const float*)Ain;
  const u16*   Ab = (const u16*)Ain;

  for (int kt = 0; kt < 4; ++kt) {
    const int k0 = kt * 64;
    if (kt) __syncthreads();
#pragma unroll
    for (int it = 0; it < 4; ++it) {
      const int s = tid + it * 256;
      const int row = s >> 3, c16 = s & 7;
      const int dst = (row << 3) | (c16 ^ (row & 7));
      const long src = (long)(m0 + row) * 256 + k0 + c16 * 8;
      int4 val;
      if constexpr (AF32) {
        const float4* p = (const float4*)(Af + src);
        const float4 x = p[0], y = p[1];
        val.x = pack2(x.x, x.y); val.y = pack2(x.z, x.w);
        val.z = pack2(y.x, y.y); val.w = pack2(y.z, y.w);
      } else {
        val = *(const int4*)(Ab + src);
      }
      ash[dst] = val;
    }
#pragma unroll
    for (int it = 0; it < 4; ++it) {
      const int s = tid + it * 256;
      const int row = s >> 3, c16 = s & 7;
      const int dst = (row << 3) | (c16 ^ (row & 7));
      wsh[dst] = *(const int4*)(W + (long)(n0 + row) * 256 + k0 + c16 * 8);
    }
    __syncthreads();
#pragma unroll
    for (int kk = 0; kk < 2; ++kk) {
      bs8 af[4], wf[4];
#pragma unroll
      for (int m = 0; m < 4; ++m) {
        const int row = wm + m * 16 + lr;
        af[m] = *(const bs8*)&ash[(row << 3) | ((kk * 4 + lk) ^ (row & 7))];
      }
#pragma unroll
      for (int n = 0; n < 4; ++n) {
        const int row = wn + n * 16 + lr;
        wf[n] = *(const bs8*)&wsh[(row << 3) | ((kk * 4 + lk) ^ (row & 7))];
      }
#pragma unroll
      for (int m = 0; m < 4; ++m)
#pragma unroll
        for (int n = 0; n < 4; ++n)
          acc[m][n] = __builtin_amdgcn_mfma_f32_16x16x32_bf16(af[m], wf[n],
                                                              acc[m][n], 0, 0, 0);
    }
  }
  // ---- epilogue ----
  if constexpr (EPI == EPI_QSM) {
#pragma unroll
    for (int m = 0; m < 4; ++m) {
      const int rb = m0 + wm + m * 16 + lk * 4;
#pragma unroll
      for (int j = 0; j < 4; ++j) {
#pragma unroll
        for (int hh = 0; hh < 2; ++hh) {
          const int c0 = n0 + wn + (2 * hh) * 16 + lr;
          const float p0 = __expf(acc[m][2 * hh][j] + bias[c0]);
          const float p1 = __expf(acc[m][2 * hh + 1][j] + bias[c0 + 16]);
          float s = p0 + p1;
#pragma unroll
          for (int o = 8; o >= 1; o >>= 1) s += __shfl_xor(s, o);
          const float inv = 1.0f / s;
          outb[(long)(rb + j) * 256 + c0]      = f2bf(p0 * inv);
          outb[(long)(rb + j) * 256 + c0 + 16] = f2bf(p1 * inv);
        }
      }
    }
  } else {
#pragma unroll
    for (int m = 0; m < 4; ++m) {
      const int rb = m0 + wm + m * 16 + lk * 4;
#pragma unroll
      for (int n = 0; n < 4; ++n) {
        const int gc = n0 + wn + n * 16 + lr;
        const float bv = bias[gc];
#pragma unroll
        for (int j = 0; j < 4; ++j) {
          const long idx = (long)(rb + j) * 256 + gc;
          float v = acc[m][n][j] + bv;
          if constexpr (EPI == EPI_GELU) v = gelu_f(v);
          if constexpr (EPI == EPI_PLAIN || EPI == EPI_GELU) {
            outb[idx] = f2bf(v);
          } else {
            const float sc = scores[(long)(rb + j) * 4 + expert];
            float base;
            if constexpr (EPI == EPI_CINIT) base = csrc[idx];
            else                            base = outf[idx];
            outf[idx] = base + sc * v;
          }
        }
      }
    }
  }
}

// ---------------------------------------------------------------------------
// kvstats: fused {K-proj, V-proj, K-softmax, per-head stats}.
// Emits tmpT[h][dv][dk] (swapped MFMA operands: V^T @ Kn) and ksum[h][dk].
// ---------------------------------------------------------------------------
__global__ __launch_bounds__(1024, 4) void kvstats(
    const float* __restrict__ Ain, const u16* __restrict__ Wk,
    const u16* __restrict__ Wv, const float* __restrict__ bk,
    const float* __restrict__ bv, float* __restrict__ pks,
    float* __restrict__ ptm) {
  __shared__ __align__(16) char smem[73728];
  int4* ash  = (int4*)smem;        // 512 slots  (64x64 bf16)
  int4* wksh = ash + 512;          // 2048 slots (256x64)
  int4* wvsh = wksh + 2048;        // 2048 slots
  u16* KnT = (u16*)smem;           // [256][72] bf16 (transposed, padded)
  u16* VT  = KnT + 256 * 72;
  const int tid = threadIdx.x;
  const int wave = tid >> 6, lane = tid & 63;
  const int lr = lane & 15, lk = lane >> 4;
  const int kvsel = wave >> 3, w3 = wave & 7;
  const int wm = (w3 >> 2) * 32, wn = (w3 & 3) * 64;
  const int b = blockIdx.y, ch = blockIdx.x;
  const long r0 = (long)b * 8192 + (long)ch * 64;

  f32x4 acc[2][4];
#pragma unroll
  for (int m = 0; m < 2; ++m)
#pragma unroll
    for (int n = 0; n < 4; ++n) acc[m][n] = f32x4{0.f, 0.f, 0.f, 0.f};

  for (int kt = 0; kt < 4; ++kt) {
    const int k0 = kt * 64;
    if (kt) __syncthreads();
    if (tid < 512) {  // A tile 64x64 fp32 -> bf16
      const int row = tid >> 3, c16 = tid & 7;
      const int dst = (row << 3) | (c16 ^ (row & 7));
      const float4* p = (const float4*)(Ain + (r0 + row) * 256 + k0 + c16 * 8);
      const float4 x = p[0], y = p[1];
      int4 val;
      val.x = pack2(x.x, x.y); val.y = pack2(x.z, x.w);
      val.z = pack2(y.x, y.y); val.w = pack2(y.z, y.w);
      ash[dst] = val;
    }
#pragma unroll
    for (int it = 0; it < 2; ++it) {  // Wk + Wv tiles 256x64
      const int s = tid + it * 1024;
      const int row = s >> 3, c16 = s & 7;
      const int dst = (row << 3) | (c16 ^ (row & 7));
      wksh[dst] = *(const int4*)(Wk + (long)row * 256 + k0 + c16 * 8);
      wvsh[dst] = *(const int4*)(Wv + (long)row * 256 + k0 + c16 * 8);
    }
    __syncthreads();
    const int4* wsh = kvsel ? wvsh : wksh;
#pragma unroll
    for (int kk = 0; kk < 2; ++kk) {
      bs8 af[2], wf[4];
#pragma unroll
      for (int m = 0; m < 2; ++m) {
        const int row = wm + m * 16 + lr;
        af[m] = *(const bs8*)&ash[(row << 3) | ((kk * 4 + lk) ^ (row & 7))];
      }
#pragma unroll
      for (int n = 0; n < 4; ++n) {
        const int row = wn + n * 16 + lr;
        wf[n] = *(const bs8*)&wsh[(row << 3) | ((kk * 4 + lk) ^ (row & 7))];
      }
#pragma unroll
      for (int m = 0; m < 2; ++m)
#pragma unroll
        for (int n = 0; n < 4; ++n)
          acc[m][n] = __builtin_amdgcn_mfma_f32_16x16x32_bf16(af[m], wf[n],
                                                              acc[m][n], 0, 0, 0);
    }
  }
  __syncthreads();  // GEMM LDS dead; reuse as KnT/VT

  const float* bias = kvsel ? bv : bk;
  if (kvsel == 0) {
#pragma unroll
    for (int m = 0; m < 2; ++m)
#pragma unroll
      for (int j = 0; j < 4; ++j)
#pragma unroll
        for (int hh = 0; hh < 2; ++hh) {
          const int c0 = wn + (2 * hh) * 16 + lr;
          const float p0 = __expf(acc[m][2 * hh][j] + bias[c0]);
          const float p1 = __expf(acc[m][2 * hh + 1][j] + bias[c0 + 16]);
          float s = p0 + p1;
#pragma unroll
          for (int o = 8; o >= 1; o >>= 1) s += __shfl_xor(s, o);
          const float inv = 1.0f / s;
          acc[m][2 * hh][j] = p0 * inv;
          acc[m][2 * hh + 1][j] = p1 * inv;
        }
  }
  {
    u16* T = kvsel ? VT : KnT;
#pragma unroll
    for (int m = 0; m < 2; ++m) {
      const int rb = wm + m * 16 + lk * 4;
#pragma unroll
      for (int n = 0; n < 4; ++n) {
        const int col = wn + n * 16 + lr;
        float v0 = acc[m][n][0], v1 = acc[m][n][1];
        float v2 = acc[m][n][2], v3 = acc[m][n][3];
        if (kvsel) {
          const float bb = bias[col];
          v0 += bb; v1 += bb; v2 += bb; v3 += bb;
        }
        uint2 w;
        w.x = pack2(v0, v1); w.y = pack2(v2, v3);
        *(uint2*)(T + col * 72 + rb) = w;
      }
    }
  }
  __syncthreads();

  if (kvsel == 0) {  // stats: wave w3 = head h
    const int h = w3;
    f32x16 aT, aK;
#pragma unroll
    for (int r = 0; r < 16; ++r) { aT[r] = 0.f; aK[r] = 0.f; }
    bs8 ones;
#pragma unroll
    for (int e = 0; e < 8; ++e) ones[e] = (short)0x3F80;
    const u16* kcol = KnT + (h * 32 + (lane & 31)) * 72;
    const u16* vcol = VT  + (h * 32 + (lane & 31)) * 72;
    const int hi8 = (lane >> 5) * 8;
#pragma unroll
    for (int ks = 0; ks < 4; ++ks) {
      const bs8 a  = *(const bs8*)(kcol + ks * 16 + hi8);
      const bs8 vb = *(const bs8*)(vcol + ks * 16 + hi8);
      aT = __builtin_amdgcn_mfma_f32_32x32x16_bf16(vb, a, aT, 0, 0, 0);  // tmpT
      aK = __builtin_amdgcn_mfma_f32_32x32x16_bf16(a, ones, aK, 0, 0, 0);
    }
    const long blk = (long)b * gridDim.x + ch;
    float* po = ptm + blk * 8192 + h * 1024;
#pragma unroll
    for (int r = 0; r < 16; ++r) {
      const int dv = (r & 3) + 8 * (r >> 2) + 4 * (lane >> 5);
      po[dv * 32 + (lane & 31)] = aT[r];   // tmpT[h][dv][dk]
    }
    if ((lane & 31) == 0) {
#pragma unroll
      for (int r = 0; r < 16; ++r) {
        const int dk = (r & 3) + 8 * (r >> 2) + 4 * (lane >> 5);
        pks[blk * 256 + h * 32 + dk] = aK[r];
      }
    }
  }
}

// deterministic reduce of the 128 chunk-partials for ONE f
__global__ void reduceStats(const float* __restrict__ pk,
                            const float* __restrict__ pt,
                            float* __restrict__ ksum, float* __restrict__ tmp) {
  const int b = blockIdx.y;
  const int i = blockIdx.x * 256 + threadIdx.x;  // 0..8447
  float s = 0.f;
  if (i < 256) {
    const float* p = pk + (long)b * 128 * 256 + i;
    for (int c = 0; c < 128; ++c) s += p[c * 256];
    ksum[(long)b * 256 + i] = s;
  } else {
    const int j = i - 256;
    const float* p = pt + (long)b * 128 * 8192 + j;
    for (int c = 0; c < 128; ++c) s += p[c * 8192];
    tmp[(long)b * 8192 + j] = s;
  }
}

// ---------------------------------------------------------------------------
// mixk (shfl-free): out = q + (1/F) sum_f alpha_f * (q @ tmp_f)
// Block = 64 rows. q tile staged in LDS (stride 264 u16, 16B aligned).
// Thread t=(h,dv) holds tmpT[f][h][dv][:] in registers (contiguous).
// Phase 1: 64*8*F alpha dots spread across 256 threads -> LDS.
// Phase 2: per row, 4 broadcast b128 q reads -> 32 regs, F*32 FMA. No shfl.
// ---------------------------------------------------------------------------
template <int F>
__global__ __launch_bounds__(256, 2) void mixk(const u16* __restrict__ q,
                                               const float* __restrict__ ksum,
                                               const float* __restrict__ tmp,
                                               u16* __restrict__ out) {
  constexpr int LF = (F == 2) ? 1 : 0;
  constexpr int QS = 264;               // u16 row stride (528 B, 16B-aligned)
  __shared__ u16 qsh[64 * QS];
  __shared__ float alsh[64][17];
  __shared__ float ksh[8][F * 36];      // padded per-head ksum
  const int t = threadIdx.x;
  const int h = t >> 5, dv = t & 31;
  const int b = blockIdx.y;
  const long row0 = (long)b * 8192 + (long)blockIdx.x * 64;

  // stage q tile (64 x 256 bf16)
#pragma unroll
  for (int it = 0; it < 8; ++it) {
    const int i = t + it * 256;
    const int r = i >> 5, c = i & 31;
    *(int4*)&qsh[r * QS + c * 8] = *(const int4*)&q[(row0 + r) * 256 + c * 8];
  }
  // ksum -> padded LDS
#pragma unroll
  for (int f = 0; f < F; ++f)
    ksh[h][f * 36 + dv] = ksum[((long)f * 4 + b) * 256 + t];
  // tmpT rows -> registers (contiguous float4 x 8 per f)
  float tr[F][32];
#pragma unroll
  for (int f = 0; f < F; ++f) {
    const float* tp = tmp + ((long)f * 4 + b) * 8192 + h * 1024 + dv * 32;
#pragma unroll
    for (int c = 0; c < 8; ++c) {
      const float4 v = *(const float4*)(tp + c * 4);
      tr[f][c * 4] = v.x; tr[f][c * 4 + 1] = v.y;
      tr[f][c * 4 + 2] = v.z; tr[f][c * 4 + 3] = v.w;
    }
  }
  __syncthreads();

  // phase 1: alphas (one dot per (r,hh,f))
  for (int d = t; d < 64 * 8 * F; d += 256) {
    const int f = d & (F - 1);
    const int hh = (d >> LF) & 7;
    const int r = d >> (3 + LF);
    const u16* qp = &qsh[r * QS + hh * 32];
    const float* kp = &ksh[hh][f * 36];
    float s = 0.f;
#pragma unroll
    for (int c = 0; c < 4; ++c) {
      const bs8 qa = *(const bs8*)(qp + c * 8);
#pragma unroll
      for (int j = 0; j < 8; ++j) s += bf2f((u16)qa[j]) * kp[c * 8 + j];
    }
    alsh[r][(hh << LF) | f] = 1.0f / s;
  }
  __syncthreads();

  // phase 2
#pragma unroll 2
  for (int r = 0; r < 64; ++r) {
    float qr[32];
    const u16* qp = &qsh[r * QS + h * 32];
#pragma unroll
    for (int c = 0; c < 4; ++c) {
      const bs8 qa = *(const bs8*)(qp + c * 8);
#pragma unroll
      for (int j = 0; j < 8; ++j) qr[c * 8 + j] = bf2f((u16)qa[j]);
    }
    float acc = 0.f;
#pragma unroll
    for (int f = 0; f < F; ++f) {
      float s0 = 0.f, s1 = 0.f;
#pragma unroll
      for (int dk = 0; dk < 32; dk += 2) {
        s0 += qr[dk] * tr[f][dk];
        s1 += qr[dk + 1] * tr[f][dk + 1];
      }
      acc += (s0 + s1) * alsh[r][(h << LF) | f];
    }
    const float qv = bf2f(qsh[r * QS + t]);
    out[(row0 + r) * 256 + t] = f2bf(qv + acc * (1.0f / (float)F));
  }
}

// pre-convert the 34 (256x256) weight matrices to bf16
struct WTab { const float* p[34]; };
__global__ void convW(WTab tab, u16* __restrict__ dst) {
  const int s = blockIdx.y;
  const long i = ((long)blockIdx.x * 256 + threadIdx.x) * 4;
  const float4 v = *(const float4*)(tab.p[s] + i);
  ushort4 o;
  o.x = f2bf(v.x); o.y = f2bf(v.y); o.z = f2bf(v.z); o.w = f2bf(v.w);
  *(ushort4*)(dst + (long)s * 65536 + i) = o;
}

// ---------------------------------------------------------------------------
extern "C" void kernel_launch(void* const* d_in, const int* in_sizes, int n_in,
                              void* d_out, int out_size, void* d_ws, size_t ws_size,
                              hipStream_t stream) {
  (void)in_sizes; (void)n_in; (void)out_size; (void)ws_size;
  const float* scores = (const float*)d_in[0];
  const float* query  = (const float*)d_in[1];
  const float* IF     = (const float*)d_in[2];
  const float* ca_Wq = (const float*)d_in[3];  const float* ca_bq = (const float*)d_in[4];
  const float* ca_Wk = (const float*)d_in[5];  const float* ca_bk = (const float*)d_in[6];
  const float* ca_Wv = (const float*)d_in[7];  const float* ca_bv = (const float*)d_in[8];
  const float* ca_Wo = (const float*)d_in[9];  const float* ca_bo = (const float*)d_in[10];
  const float* sa_Wq = (const float*)d_in[11]; const float* sa_bq = (const float*)d_in[12];
  const float* sa_Wk = (const float*)d_in[13]; const float* sa_bk = (const float*)d_in[14];
  const float* sa_Wv = (const float*)d_in[15]; const float* sa_bv = (const float*)d_in[16];
  const float* sa_Wo = (const float*)d_in[17]; const float* sa_bo = (const float*)d_in[18];
  const float* f1W1 = (const float*)d_in[19]; const float* f1b1 = (const float*)d_in[20];
  const float* f1W2 = (const float*)d_in[21]; const float* f1b2 = (const float*)d_in[22];
  const float* f1W3 = (const float*)d_in[23]; const float* f1b3 = (const float*)d_in[24];
  const float* f2W1 = (const float*)d_in[25]; const float* f2b1 = (const float*)d_in[26];
  const float* f2W2 = (const float*)d_in[27]; const float* f2b2 = (const float*)d_in[28];
  const float* f2W3 = (const float*)d_in[29]; const float* f2b3 = (const float*)d_in[30];

  char* ws = (char*)d_ws;
  u16* X0 = (u16*)(ws);                   // (M,256) bf16, 16 MiB each
  u16* X1 = (u16*)(ws + 16777216);
  u16* X2 = (u16*)(ws + 33554432);
  u16* X3 = (u16*)(ws + 50331648);        // FFN intermediate; doubles as ptm
  float* ptmX3 = (float*)(ws + 50331648); // 4b x 128ch x 8192 f32 = 16.78 MB
  u16* W16 = (u16*)(ws + 67108864);       // 34 * 65536 bf16
  float* ksum = (float*)(ws + 71565312);  // [F*B][256]
  float* tmpb = (float*)(ws + 71573504);  // [F*B][8192]  (tmpT layout)
  float* pks  = (float*)(ws + 71835648);  // partial ksum
  float* qacc = (float*)d_out;            // fp32 accumulator = output

  WTab tab;
  tab.p[0] = ca_Wq; tab.p[1] = ca_Wk; tab.p[2] = ca_Wk + 65536;
  tab.p[3] = ca_Wv; tab.p[4] = ca_Wv + 65536; tab.p[5] = ca_Wo;
  tab.p[6] = sa_Wq; tab.p[7] = sa_Wk; tab.p[8] = sa_Wv; tab.p[9] = sa_Wo;
  for (int e = 0; e < 4; ++e) {
    tab.p[10 + e] = f1W1 + e * 65536; tab.p[14 + e] = f1W2 + e * 65536;
    tab.p[18 + e] = f1W3 + e * 65536; tab.p[22 + e] = f2W1 + e * 65536;
    tab.p[26 + e] = f2W2 + e * 65536; tab.p[30 + e] = f2W3 + e * 65536;
  }
  convW<<<dim3(64, 34), 256, 0, stream>>>(tab, W16);

  const dim3 gg(256, 2), gb(256);
  const dim3 kvg(128, 4), kvb(1024);
  // ---- cross attention ----
  gemm256<true, EPI_QSM><<<gg, gb, 0, stream>>>(query, W16 + 0 * 65536L, ca_bq, X0, nullptr, nullptr, nullptr, 0);
  for (int f = 0; f < 2; ++f) {
    kvstats<<<kvg, kvb, 0, stream>>>(IF + (long)f * 8388608,
                                     W16 + (1 + f) * 65536L, W16 + (3 + f) * 65536L,
                                     ca_bk + f * 256, ca_bv + f * 256, pks, ptmX3);
    reduceStats<<<dim3(33, 4), 256, 0, stream>>>(pks, ptmX3, ksum + f * 4 * 256, tmpb + (long)f * 4 * 8192);
  }
  mixk<2><<<dim3(128, 4), 256, 0, stream>>>(X0, ksum, tmpb, X1);
  gemm256<false, EPI_PLAIN><<<gg, gb, 0, stream>>>(X1, W16 + 5 * 65536L, ca_bo, X2, nullptr, nullptr, nullptr, 0);
  for (int e = 0; e < 4; ++e) {  // FFN1 + combine into qacc, init from query
    gemm256<false, EPI_GELU><<<gg, gb, 0, stream>>>(X2, W16 + (10 + e) * 65536L, f1b1 + e * 256, X0, nullptr, nullptr, nullptr, 0);
    gemm256<false, EPI_GELU><<<gg, gb, 0, stream>>>(X0, W16 + (14 + e) * 65536L, f1b2 + e * 256, X3, nullptr, nullptr, nullptr, 0);
    if (e == 0)
      gemm256<false, EPI_CINIT><<<gg, gb, 0, stream>>>(X3, W16 + (18 + e) * 65536L, f1b3 + e * 256, nullptr, qacc, query, scores, e);
    else
      gemm256<false, EPI_CACC><<<gg, gb, 0, stream>>>(X3, W16 + (18 + e) * 65536L, f1b3 + e * 256, nullptr, qacc, nullptr, scores, e);
  }
  // ---- self attention ----
  gemm256<true, EPI_QSM><<<gg, gb, 0, stream>>>(qacc, W16 + 6 * 65536L, sa_bq, X0, nullptr, nullptr, nullptr, 0);
  kvstats<<<kvg, kvb, 0, stream>>>(qacc, W16 + 7 * 65536L, W16 + 8 * 65536L,
                                   sa_bk, sa_bv, pks, ptmX3);
  reduceStats<<<dim3(33, 4), 256, 0, stream>>>(pks, ptmX3, ksum, tmpb);
  mixk<1><<<dim3(128, 4), 256, 0, stream>>>(X0, ksum, tmpb, X1);
  gemm256<false, EPI_PLAIN><<<gg, gb, 0, stream>>>(X1, W16 + 9 * 65536L, sa_bo, X2, nullptr, nullptr, nullptr, 0);
  for (int e = 0; e < 4; ++e) {  // FFN2 + combine (in place on qacc)
    gemm256<false, EPI_GELU><<<gg, gb, 0, stream>>>(X2, W16 + (22 + e) * 65536L, f2b1 + e * 256, X0, nullptr, nullptr, nullptr, 0);
    gemm256<false, EPI_GELU><<<gg, gb, 0, stream>>>(X0, W16 + (26 + e) * 65536L, f2b2 + e * 256, X3, nullptr, nullptr, nullptr, 0);
    if (e == 0)
      gemm256<false, EPI_CINIT><<<gg, gb, 0, stream>>>(X3, W16 + (30 + e) * 65536L, f2b3 + e * 256, nullptr, qacc, qacc, scores, e);
    else
      gemm256<false, EPI_CACC><<<gg, gb, 0, stream>>>(X3, W16 + (30 + e) * 65536L, f2b3 + e * 256, nullptr, qacc, nullptr, scores, e);
  }
}

// Round 6
// 449.841 us; speedup vs baseline: 2.8525x; 1.2540x over previous
//
#include <hip/hip_runtime.h>

// ---------------------------------------------------------------------------
// HeterogeneousNormalizedAttentionBlock on MI355X (gfx950)
// B=4, LQ=LK=8192, E=256, H=8, D=32, NF=2, NE=4, HID=256;  M = B*LQ = 32768
// ---------------------------------------------------------------------------

typedef unsigned short u16;
typedef __attribute__((ext_vector_type(8))) short   bs8;    // 8 x bf16
typedef __attribute__((ext_vector_type(4))) float   f32x4;
typedef __attribute__((ext_vector_type(16))) float  f32x16;

__device__ __forceinline__ float bf2f(u16 u) {
  union { float f; unsigned i; } c; c.i = ((unsigned)u) << 16; return c.f;
}
__device__ __forceinline__ u16 f2bf(float f) {
  union { float f; unsigned i; } c; c.f = f;
  unsigned x = c.i;
  return (u16)((x + 0x7fffu + ((x >> 16) & 1u)) >> 16);   // RNE
}
__device__ __forceinline__ unsigned pack2(float a, float b) {
  return (unsigned)f2bf(a) | ((unsigned)f2bf(b) << 16);
}
__device__ __forceinline__ float gelu_f(float x) {
  const float t = x * (0.7978845608f + 0.0356774081f * x * x);
  return x / (1.f + __expf(-2.f * t));
}

#define EPI_PLAIN 0
#define EPI_QSM   4   // feature-dim softmax over 32-col head groups

// ---------------------------------------------------------------------------
// Attention-side GEMM: C(M,256) = epi(A(M,256) @ W(256,256)^T + bias)
// BM=BN=128, BK=64, 4 waves (2x2), wave 64x64. XOR-swizzled LDS.
// ---------------------------------------------------------------------------
template <bool AF32, int EPI>
__global__ __launch_bounds__(256, 2) void gemm256(
    const void* __restrict__ Ain, const u16* __restrict__ W,
    const float* __restrict__ bias, u16* __restrict__ outb) {
  __shared__ int4 ash[1024];  // 128 x 64 bf16, swizzled
  __shared__ int4 wsh[1024];
  const int tid = threadIdx.x;
  const int m0 = blockIdx.x * 128, n0 = blockIdx.y * 128;
  const int wave = tid >> 6, lane = tid & 63;
  const int wm = (wave >> 1) * 64, wn = (wave & 1) * 64;
  const int lr = lane & 15, lk = lane >> 4;
  f32x4 acc[4][4];
#pragma unroll
  for (int m = 0; m < 4; ++m)
#pragma unroll
    for (int n = 0; n < 4; ++n) acc[m][n] = f32x4{0.f, 0.f, 0.f, 0.f};

  const float* Af = (const float*)Ain;
  const u16*   Ab = (const u16*)Ain;

  for (int kt = 0; kt < 4; ++kt) {
    const int k0 = kt * 64;
    if (kt) __syncthreads();
#pragma unroll
    for (int it = 0; it < 4; ++it) {
      const int s = tid + it * 256;
      const int row = s >> 3, c16 = s & 7;
      const int dst = (row << 3) | (c16 ^ (row & 7));
      const long src = (long)(m0 + row) * 256 + k0 + c16 * 8;
      int4 val;
      if constexpr (AF32) {
        const float4* p = (const float4*)(Af + src);
        const float4 x = p[0], y = p[1];
        val.x = pack2(x.x, x.y); val.y = pack2(x.z, x.w);
        val.z = pack2(y.x, y.y); val.w = pack2(y.z, y.w);
      } else {
        val = *(const int4*)(Ab + src);
      }
      ash[dst] = val;
    }
#pragma unroll
    for (int it = 0; it < 4; ++it) {
      const int s = tid + it * 256;
      const int row = s >> 3, c16 = s & 7;
      const int dst = (row << 3) | (c16 ^ (row & 7));
      wsh[dst] = *(const int4*)(W + (long)(n0 + row) * 256 + k0 + c16 * 8);
    }
    __syncthreads();
#pragma unroll
    for (int kk = 0; kk < 2; ++kk) {
      bs8 af[4], wf[4];
#pragma unroll
      for (int m = 0; m < 4; ++m) {
        const int row = wm + m * 16 + lr;
        af[m] = *(const bs8*)&ash[(row << 3) | ((kk * 4 + lk) ^ (row & 7))];
      }
#pragma unroll
      for (int n = 0; n < 4; ++n) {
        const int row = wn + n * 16 + lr;
        wf[n] = *(const bs8*)&wsh[(row << 3) | ((kk * 4 + lk) ^ (row & 7))];
      }
#pragma unroll
      for (int m = 0; m < 4; ++m)
#pragma unroll
        for (int n = 0; n < 4; ++n)
          acc[m][n] = __builtin_amdgcn_mfma_f32_16x16x32_bf16(af[m], wf[n],
                                                              acc[m][n], 0, 0, 0);
    }
  }
  // ---- epilogue ----
  if constexpr (EPI == EPI_QSM) {
#pragma unroll
    for (int m = 0; m < 4; ++m) {
      const int rb = m0 + wm + m * 16 + lk * 4;
#pragma unroll
      for (int j = 0; j < 4; ++j) {
#pragma unroll
        for (int hh = 0; hh < 2; ++hh) {
          const int c0 = n0 + wn + (2 * hh) * 16 + lr;
          const float p0 = __expf(acc[m][2 * hh][j] + bias[c0]);
          const float p1 = __expf(acc[m][2 * hh + 1][j] + bias[c0 + 16]);
          float s = p0 + p1;
#pragma unroll
          for (int o = 8; o >= 1; o >>= 1) s += __shfl_xor(s, o);
          const float inv = 1.0f / s;
          outb[(long)(rb + j) * 256 + c0]      = f2bf(p0 * inv);
          outb[(long)(rb + j) * 256 + c0 + 16] = f2bf(p1 * inv);
        }
      }
    }
  } else {
#pragma unroll
    for (int m = 0; m < 4; ++m) {
      const int rb = m0 + wm + m * 16 + lk * 4;
#pragma unroll
      for (int n = 0; n < 4; ++n) {
        const int gc = n0 + wn + n * 16 + lr;
        const float bv = bias[gc];
#pragma unroll
        for (int j = 0; j < 4; ++j)
          outb[(long)(rb + j) * 256 + gc] = f2bf(acc[m][n][j] + bv);
      }
    }
  }
}

// ---------------------------------------------------------------------------
// ffn4 v2: fused 4-expert 3-layer FFN + score-weighted combine + residual.
// BM=64 (grid 512), 8 waves (2Mx4N, wave 32x64), BK=32.
// xsh: persistent 64x256 x-tile (fixes stale-absh bug).
// wsh: FULL 256x32 W K-tile (fixes half-staged OOB bug).
// hsh: 64x256 h tile.  80KB LDS total -> 2 blocks/CU.
// ---------------------------------------------------------------------------
__global__ __launch_bounds__(512, 4) void ffn4(
    const u16* __restrict__ X, const u16* __restrict__ Wbase,
    int w1slot, int w2slot, int w3slot,
    const float* __restrict__ b1, const float* __restrict__ b2,
    const float* __restrict__ b3, const float* __restrict__ scores,
    const float* __restrict__ csrc, float* __restrict__ outf) {
  __shared__ int4 xsh[2048];   // 32KB: x 64x256, chunk-XOR8
  __shared__ int4 hsh[2048];   // 32KB: h 64x256, chunk-XOR8
  __shared__ int4 wsh[1024];   // 16KB: W 256x32 K-tile, chunk-XOR4
  const int tid = threadIdx.x, wave = tid >> 6, lane = tid & 63;
  const int wm = (wave >> 2) * 32, wn = (wave & 3) * 64;
  const int lr = lane & 15, lk = lane >> 4;
  const long m0 = (long)blockIdx.x * 64;

  // stage x once (64 x 256 bf16)
#pragma unroll
  for (int it = 0; it < 4; ++it) {
    const int s = tid + it * 512;
    const int row = s >> 5, c8 = s & 31;
    const int cs = (c8 & 24) | ((c8 ^ row) & 7);
    xsh[row * 32 + cs] = *(const int4*)(X + (m0 + row) * 256 + c8 * 8);
  }
  // (visibility guaranteed by first kt-loop barrier)

  f32x4 oacc[2][4];
#pragma unroll
  for (int m = 0; m < 2; ++m)
#pragma unroll
    for (int n = 0; n < 4; ++n) oacc[m][n] = f32x4{0.f, 0.f, 0.f, 0.f};
  f32x4 acc[2][4];

  for (int e = 0; e < 4; ++e) {
#pragma unroll 1
    for (int l = 0; l < 3; ++l) {
      const int slot = (l == 0 ? w1slot : (l == 1 ? w2slot : w3slot)) + e;
      const u16* Wl = Wbase + (long)slot * 65536;
      const int4* asrc = (l == 0) ? xsh : hsh;
#pragma unroll
      for (int m = 0; m < 2; ++m)
#pragma unroll
        for (int n = 0; n < 4; ++n) acc[m][n] = f32x4{0.f, 0.f, 0.f, 0.f};
      for (int kt = 0; kt < 8; ++kt) {
        __syncthreads();   // wsh reuse guard (+ xsh/hsh write visibility)
#pragma unroll
        for (int it = 0; it < 2; ++it) {  // full 256 rows x 32 cols
          const int s = tid + it * 512;
          const int row = s >> 2, c4 = s & 3;
          wsh[row * 4 + (c4 ^ (row & 3))] =
              *(const int4*)(Wl + (long)row * 256 + kt * 32 + c4 * 8);
        }
        __syncthreads();
        bs8 af[2], wf[4];
        const int c8 = kt * 4 + lk;
#pragma unroll
        for (int m = 0; m < 2; ++m) {
          const int row = wm + m * 16 + lr;
          const int cs = (c8 & 24) | ((c8 ^ row) & 7);
          af[m] = *(const bs8*)&asrc[row * 32 + cs];
        }
#pragma unroll
        for (int n = 0; n < 4; ++n) {
          const int row = wn + n * 16 + lr;
          wf[n] = *(const bs8*)&wsh[row * 4 + ((lk ^ row) & 3)];
        }
#pragma unroll
        for (int m = 0; m < 2; ++m)
#pragma unroll
          for (int n = 0; n < 4; ++n)
            acc[m][n] = __builtin_amdgcn_mfma_f32_16x16x32_bf16(
                af[m], wf[n], acc[m][n], 0, 0, 0);
      }
      __syncthreads();   // all reads of asrc done before hsh overwrite
      if (l < 2) {
        const float* bb = (l == 0 ? b1 : b2) + e * 256;
        u16* hp = (u16*)hsh;
#pragma unroll
        for (int m = 0; m < 2; ++m)
#pragma unroll
          for (int n = 0; n < 4; ++n) {
            const int col = wn + n * 16 + lr;
            const float bv = bb[col];
            const int c8w = col >> 3;
#pragma unroll
            for (int j = 0; j < 4; ++j) {
              const int row = wm + m * 16 + lk * 4 + j;
              const int cs = (c8w & 24) | ((c8w ^ row) & 7);
              hp[row * 256 + cs * 8 + (col & 7)] =
                  f2bf(gelu_f(acc[m][n][j] + bv));
            }
          }
      } else {  // + b3, score-weighted accumulate (registers only)
#pragma unroll
        for (int m = 0; m < 2; ++m) {
#pragma unroll
          for (int j = 0; j < 4; ++j) {
            const float sc = scores[(m0 + wm + m * 16 + lk * 4 + j) * 4 + e];
#pragma unroll
            for (int n = 0; n < 4; ++n)
              oacc[m][n][j] +=
                  sc * (acc[m][n][j] + b3[e * 256 + wn + n * 16 + lr]);
          }
        }
      }
    }
  }
  // ---- epilogue: out = csrc + oacc ----
#pragma unroll
  for (int m = 0; m < 2; ++m) {
#pragma unroll
    for (int n = 0; n < 4; ++n) {
      const int col = wn + n * 16 + lr;
#pragma unroll
      for (int j = 0; j < 4; ++j) {
        const long idx = (m0 + wm + m * 16 + lk * 4 + j) * 256 + col;
        outf[idx] = csrc[idx] + oacc[m][n][j];
      }
    }
  }
}

// ---------------------------------------------------------------------------
// kvstats: fused {K-proj, V-proj, K-softmax, per-head stats}.
// Emits tmpT[h][dv][dk] (swapped MFMA operands: V^T @ Kn) and ksum[h][dk].
// ---------------------------------------------------------------------------
__global__ __launch_bounds__(1024, 4) void kvstats(
    const float* __restrict__ Ain, const u16* __restrict__ Wk,
    const u16* __restrict__ Wv, const float* __restrict__ bk,
    const float* __restrict__ bv, float* __restrict__ pks,
    float* __restrict__ ptm) {
  __shared__ __align__(16) char smem[73728];
  int4* ash  = (int4*)smem;        // 512 slots  (64x64 bf16)
  int4* wksh = ash + 512;          // 2048 slots (256x64)
  int4* wvsh = wksh + 2048;        // 2048 slots
  u16* KnT = (u16*)smem;           // [256][72] bf16 (transposed, padded)
  u16* VT  = KnT + 256 * 72;
  const int tid = threadIdx.x;
  const int wave = tid >> 6, lane = tid & 63;
  const int lr = lane & 15, lk = lane >> 4;
  const int kvsel = wave >> 3, w3 = wave & 7;
  const int wm = (w3 >> 2) * 32, wn = (w3 & 3) * 64;
  const int b = blockIdx.y, ch = blockIdx.x;
  const long r0 = (long)b * 8192 + (long)ch * 64;

  f32x4 acc[2][4];
#pragma unroll
  for (int m = 0; m < 2; ++m)
#pragma unroll
    for (int n = 0; n < 4; ++n) acc[m][n] = f32x4{0.f, 0.f, 0.f, 0.f};

  for (int kt = 0; kt < 4; ++kt) {
    const int k0 = kt * 64;
    if (kt) __syncthreads();
    if (tid < 512) {  // A tile 64x64 fp32 -> bf16
      const int row = tid >> 3, c16 = tid & 7;
      const int dst = (row << 3) | (c16 ^ (row & 7));
      const float4* p = (const float4*)(Ain + (r0 + row) * 256 + k0 + c16 * 8);
      const float4 x = p[0], y = p[1];
      int4 val;
      val.x = pack2(x.x, x.y); val.y = pack2(x.z, x.w);
      val.z = pack2(y.x, y.y); val.w = pack2(y.z, y.w);
      ash[dst] = val;
    }
#pragma unroll
    for (int it = 0; it < 2; ++it) {  // Wk + Wv tiles 256x64
      const int s = tid + it * 1024;
      const int row = s >> 3, c16 = s & 7;
      const int dst = (row << 3) | (c16 ^ (row & 7));
      wksh[dst] = *(const int4*)(Wk + (long)row * 256 + k0 + c16 * 8);
      wvsh[dst] = *(const int4*)(Wv + (long)row * 256 + k0 + c16 * 8);
    }
    __syncthreads();
    const int4* wsh = kvsel ? wvsh : wksh;
#pragma unroll
    for (int kk = 0; kk < 2; ++kk) {
      bs8 af[2], wf[4];
#pragma unroll
      for (int m = 0; m < 2; ++m) {
        const int row = wm + m * 16 + lr;
        af[m] = *(const bs8*)&ash[(row << 3) | ((kk * 4 + lk) ^ (row & 7))];
      }
#pragma unroll
      for (int n = 0; n < 4; ++n) {
        const int row = wn + n * 16 + lr;
        wf[n] = *(const bs8*)&wsh[(row << 3) | ((kk * 4 + lk) ^ (row & 7))];
      }
#pragma unroll
      for (int m = 0; m < 2; ++m)
#pragma unroll
        for (int n = 0; n < 4; ++n)
          acc[m][n] = __builtin_amdgcn_mfma_f32_16x16x32_bf16(af[m], wf[n],
                                                              acc[m][n], 0, 0, 0);
    }
  }
  __syncthreads();  // GEMM LDS dead; reuse as KnT/VT

  const float* bias = kvsel ? bv : bk;
  if (kvsel == 0) {
#pragma unroll
    for (int m = 0; m < 2; ++m)
#pragma unroll
      for (int j = 0; j < 4; ++j)
#pragma unroll
        for (int hh = 0; hh < 2; ++hh) {
          const int c0 = wn + (2 * hh) * 16 + lr;
          const float p0 = __expf(acc[m][2 * hh][j] + bias[c0]);
          const float p1 = __expf(acc[m][2 * hh + 1][j] + bias[c0 + 16]);
          float s = p0 + p1;
#pragma unroll
          for (int o = 8; o >= 1; o >>= 1) s += __shfl_xor(s, o);
          const float inv = 1.0f / s;
          acc[m][2 * hh][j] = p0 * inv;
          acc[m][2 * hh + 1][j] = p1 * inv;
        }
  }
  {
    u16* T = kvsel ? VT : KnT;
#pragma unroll
    for (int m = 0; m < 2; ++m) {
      const int rb = wm + m * 16 + lk * 4;
#pragma unroll
      for (int n = 0; n < 4; ++n) {
        const int col = wn + n * 16 + lr;
        float v0 = acc[m][n][0], v1 = acc[m][n][1];
        float v2 = acc[m][n][2], v3 = acc[m][n][3];
        if (kvsel) {
          const float bb = bias[col];
          v0 += bb; v1 += bb; v2 += bb; v3 += bb;
        }
        uint2 w;
        w.x = pack2(v0, v1); w.y = pack2(v2, v3);
        *(uint2*)(T + col * 72 + rb) = w;
      }
    }
  }
  __syncthreads();

  if (kvsel == 0) {  // stats: wave w3 = head h
    const int h = w3;
    f32x16 aT, aK;
#pragma unroll
    for (int r = 0; r < 16; ++r) { aT[r] = 0.f; aK[r] = 0.f; }
    bs8 ones;
#pragma unroll
    for (int e = 0; e < 8; ++e) ones[e] = (short)0x3F80;
    const u16* kcol = KnT + (h * 32 + (lane & 31)) * 72;
    const u16* vcol = VT  + (h * 32 + (lane & 31)) * 72;
    const int hi8 = (lane >> 5) * 8;
#pragma unroll
    for (int ks = 0; ks < 4; ++ks) {
      const bs8 a  = *(const bs8*)(kcol + ks * 16 + hi8);
      const bs8 vb = *(const bs8*)(vcol + ks * 16 + hi8);
      aT = __builtin_amdgcn_mfma_f32_32x32x16_bf16(vb, a, aT, 0, 0, 0);  // tmpT
      aK = __builtin_amdgcn_mfma_f32_32x32x16_bf16(a, ones, aK, 0, 0, 0);
    }
    const long blk = (long)b * gridDim.x + ch;
    float* po = ptm + blk * 8192 + h * 1024;
#pragma unroll
    for (int r = 0; r < 16; ++r) {
      const int dv = (r & 3) + 8 * (r >> 2) + 4 * (lane >> 5);
      po[dv * 32 + (lane & 31)] = aT[r];   // tmpT[h][dv][dk]
    }
    if ((lane & 31) == 0) {
#pragma unroll
      for (int r = 0; r < 16; ++r) {
        const int dk = (r & 3) + 8 * (r >> 2) + 4 * (lane >> 5);
        pks[blk * 256 + h * 32 + dk] = aK[r];
      }
    }
  }
}

// deterministic reduce of the 128 chunk-partials for ONE f
__global__ void reduceStats(const float* __restrict__ pk,
                            const float* __restrict__ pt,
                            float* __restrict__ ksum, float* __restrict__ tmp) {
  const int b = blockIdx.y;
  const int i = blockIdx.x * 256 + threadIdx.x;  // 0..8447
  float s = 0.f;
  if (i < 256) {
    const float* p = pk + (long)b * 128 * 256 + i;
    for (int c = 0; c < 128; ++c) s += p[c * 256];
    ksum[(long)b * 256 + i] = s;
  } else {
    const int j = i - 256;
    const float* p = pt + (long)b * 128 * 8192 + j;
    for (int c = 0; c < 128; ++c) s += p[c * 8192];
    tmp[(long)b * 8192 + j] = s;
  }
}

// ---------------------------------------------------------------------------
// mixk (shfl-free): out = q + (1/F) sum_f alpha_f * (q @ tmp_f)
// ---------------------------------------------------------------------------
template <int F>
__global__ __launch_bounds__(256, 2) void mixk(const u16* __restrict__ q,
                                               const float* __restrict__ ksum,
                                               const float* __restrict__ tmp,
                                               u16* __restrict__ out) {
  constexpr int LF = (F == 2) ? 1 : 0;
  constexpr int QS = 264;               // u16 row stride (528 B, 16B-aligned)
  __shared__ u16 qsh[64 * QS];
  __shared__ float alsh[64][17];
  __shared__ float ksh[8][F * 36];      // padded per-head ksum
  const int t = threadIdx.x;
  const int h = t >> 5, dv = t & 31;
  const int b = blockIdx.y;
  const long row0 = (long)b * 8192 + (long)blockIdx.x * 64;

#pragma unroll
  for (int it = 0; it < 8; ++it) {
    const int i = t + it * 256;
    const int r = i >> 5, c = i & 31;
    *(int4*)&qsh[r * QS + c * 8] = *(const int4*)&q[(row0 + r) * 256 + c * 8];
  }
#pragma unroll
  for (int f = 0; f < F; ++f)
    ksh[h][f * 36 + dv] = ksum[((long)f * 4 + b) * 256 + t];
  float tr[F][32];
#pragma unroll
  for (int f = 0; f < F; ++f) {
    const float* tp = tmp + ((long)f * 4 + b) * 8192 + h * 1024 + dv * 32;
#pragma unroll
    for (int c = 0; c < 8; ++c) {
      const float4 v = *(const float4*)(tp + c * 4);
      tr[f][c * 4] = v.x; tr[f][c * 4 + 1] = v.y;
      tr[f][c * 4 + 2] = v.z; tr[f][c * 4 + 3] = v.w;
    }
  }
  __syncthreads();

  for (int d = t; d < 64 * 8 * F; d += 256) {
    const int f = d & (F - 1);
    const int hh = (d >> LF) & 7;
    const int r = d >> (3 + LF);
    const u16* qp = &qsh[r * QS + hh * 32];
    const float* kp = &ksh[hh][f * 36];
    float s = 0.f;
#pragma unroll
    for (int c = 0; c < 4; ++c) {
      const bs8 qa = *(const bs8*)(qp + c * 8);
#pragma unroll
      for (int j = 0; j < 8; ++j) s += bf2f((u16)qa[j]) * kp[c * 8 + j];
    }
    alsh[r][(hh << LF) | f] = 1.0f / s;
  }
  __syncthreads();

#pragma unroll 2
  for (int r = 0; r < 64; ++r) {
    float qr[32];
    const u16* qp = &qsh[r * QS + h * 32];
#pragma unroll
    for (int c = 0; c < 4; ++c) {
      const bs8 qa = *(const bs8*)(qp + c * 8);
#pragma unroll
      for (int j = 0; j < 8; ++j) qr[c * 8 + j] = bf2f((u16)qa[j]);
    }
    float acc = 0.f;
#pragma unroll
    for (int f = 0; f < F; ++f) {
      float s0 = 0.f, s1 = 0.f;
#pragma unroll
      for (int dk = 0; dk < 32; dk += 2) {
        s0 += qr[dk] * tr[f][dk];
        s1 += qr[dk + 1] * tr[f][dk + 1];
      }
      acc += (s0 + s1) * alsh[r][(h << LF) | f];
    }
    const float qv = bf2f(qsh[r * QS + t]);
    out[(row0 + r) * 256 + t] = f2bf(qv + acc * (1.0f / (float)F));
  }
}

// pre-convert the 34 (256x256) weight matrices to bf16
struct WTab { const float* p[34]; };
__global__ void convW(WTab tab, u16* __restrict__ dst) {
  const int s = blockIdx.y;
  const long i = ((long)blockIdx.x * 256 + threadIdx.x) * 4;
  const float4 v = *(const float4*)(tab.p[s] + i);
  ushort4 o;
  o.x = f2bf(v.x); o.y = f2bf(v.y); o.z = f2bf(v.z); o.w = f2bf(v.w);
  *(ushort4*)(dst + (long)s * 65536 + i) = o;
}

// ---------------------------------------------------------------------------
extern "C" void kernel_launch(void* const* d_in, const int* in_sizes, int n_in,
                              void* d_out, int out_size, void* d_ws, size_t ws_size,
                              hipStream_t stream) {
  (void)in_sizes; (void)n_in; (void)out_size; (void)ws_size;
  const float* scores = (const float*)d_in[0];
  const float* query  = (const float*)d_in[1];
  const float* IF     = (const float*)d_in[2];
  const float* ca_Wq = (const float*)d_in[3];  const float* ca_bq = (const float*)d_in[4];
  const float* ca_Wk = (const float*)d_in[5];  const float* ca_bk = (const float*)d_in[6];
  const float* ca_Wv = (const float*)d_in[7];  const float* ca_bv = (const float*)d_in[8];
  const float* ca_Wo = (const float*)d_in[9];  const float* ca_bo = (const float*)d_in[10];
  const float* sa_Wq = (const float*)d_in[11]; const float* sa_bq = (const float*)d_in[12];
  const float* sa_Wk = (const float*)d_in[13]; const float* sa_bk = (const float*)d_in[14];
  const float* sa_Wv = (const float*)d_in[15]; const float* sa_bv = (const float*)d_in[16];
  const float* sa_Wo = (const float*)d_in[17]; const float* sa_bo = (const float*)d_in[18];
  const float* f1W1 = (const float*)d_in[19]; const float* f1b1 = (const float*)d_in[20];
  const float* f1W2 = (const float*)d_in[21]; const float* f1b2 = (const float*)d_in[22];
  const float* f1W3 = (const float*)d_in[23]; const float* f1b3 = (const float*)d_in[24];
  const float* f2W1 = (const float*)d_in[25]; const float* f2b1 = (const float*)d_in[26];
  const float* f2W2 = (const float*)d_in[27]; const float* f2b2 = (const float*)d_in[28];
  const float* f2W3 = (const float*)d_in[29]; const float* f2b3 = (const float*)d_in[30];

  char* ws = (char*)d_ws;
  u16* X0 = (u16*)(ws);                   // (M,256) bf16, 16 MiB each
  u16* X1 = (u16*)(ws + 16777216);
  u16* X2 = (u16*)(ws + 33554432);
  float* ptmX3 = (float*)(ws + 50331648); // 4b x 128ch x 8192 f32 = 16.78 MB
  u16* W16 = (u16*)(ws + 67108864);       // 34 * 65536 bf16
  float* ksum = (float*)(ws + 71565312);  // [F*B][256]
  float* tmpb = (float*)(ws + 71573504);  // [F*B][8192]  (tmpT layout)
  float* pks  = (float*)(ws + 71835648);  // partial ksum
  float* qacc = (float*)d_out;            // fp32 accumulator = output

  WTab tab;
  tab.p[0] = ca_Wq; tab.p[1] = ca_Wk; tab.p[2] = ca_Wk + 65536;
  tab.p[3] = ca_Wv; tab.p[4] = ca_Wv + 65536; tab.p[5] = ca_Wo;
  tab.p[6] = sa_Wq; tab.p[7] = sa_Wk; tab.p[8] = sa_Wv; tab.p[9] = sa_Wo;
  for (int e = 0; e < 4; ++e) {
    tab.p[10 + e] = f1W1 + e * 65536; tab.p[14 + e] = f1W2 + e * 65536;
    tab.p[18 + e] = f1W3 + e * 65536; tab.p[22 + e] = f2W1 + e * 65536;
    tab.p[26 + e] = f2W2 + e * 65536; tab.p[30 + e] = f2W3 + e * 65536;
  }
  convW<<<dim3(64, 34), 256, 0, stream>>>(tab, W16);

  const dim3 gg(256, 2), gb(256);
  const dim3 kvg(128, 4), kvb(1024);
  // ---- cross attention ----
  gemm256<true, EPI_QSM><<<gg, gb, 0, stream>>>(query, W16 + 0 * 65536L, ca_bq, X0);
  for (int f = 0; f < 2; ++f) {
    kvstats<<<kvg, kvb, 0, stream>>>(IF + (long)f * 8388608,
                                     W16 + (1 + f) * 65536L, W16 + (3 + f) * 65536L,
                                     ca_bk + f * 256, ca_bv + f * 256, pks, ptmX3);
    reduceStats<<<dim3(33, 4), 256, 0, stream>>>(pks, ptmX3, ksum + f * 4 * 256, tmpb + (long)f * 4 * 8192);
  }
  mixk<2><<<dim3(128, 4), 256, 0, stream>>>(X0, ksum, tmpb, X1);
  gemm256<false, EPI_PLAIN><<<gg, gb, 0, stream>>>(X1, W16 + 5 * 65536L, ca_bo, X2);
  ffn4<<<512, 512, 0, stream>>>(X2, W16, 10, 14, 18, f1b1, f1b2, f1b3, scores, query, qacc);
  // ---- self attention ----
  gemm256<true, EPI_QSM><<<gg, gb, 0, stream>>>(qacc, W16 + 6 * 65536L, sa_bq, X0);
  kvstats<<<kvg, kvb, 0, stream>>>(qacc, W16 + 7 * 65536L, W16 + 8 * 65536L,
                                   sa_bk, sa_bv, pks, ptmX3);
  reduceStats<<<dim3(33, 4), 256, 0, stream>>>(pks, ptmX3, ksum, tmpb);
  mixk<1><<<dim3(128, 4), 256, 0, stream>>>(X0, ksum, tmpb, X1);
  gemm256<false, EPI_PLAIN><<<gg, gb, 0, stream>>>(X1, W16 + 9 * 65536L, sa_bo, X2);
  ffn4<<<512, 512, 0, stream>>>(X2, W16, 22, 26, 30, f2b1, f2b2, f2b3, scores, qacc, qacc);
}